// Round 3
// baseline (64.260 us; speedup 1.0000x reference)
//
#include <hip/hip_runtime.h>

// Problem constants (match reference)
#define PP 32   // patches
#define SS 4
#define CC 64
#define HH 128
#define WW 128
#define NC 32   // channels kept per patch
#define OO 32   // adaptive pool output size (MIN_SIZE)

struct Params { int size, offy, offx, pad; };

// Tiny setup kernel: hoist per-patch div/mod out of the hot kernel.
__global__ __launch_bounds__(64) void setup_params_kernel(
    const int* __restrict__ size_raw,
    const int* __restrict__ pix,
    Params*    __restrict__ prm)
{
    const int p = threadIdx.x;
    if (p < PP) {
        const int size = size_raw[p] + OO;      // [32,128]
        const int wr = WW - size + 1;
        const int hr = HH - size + 1;
        const int pm = pix[p] % (wr * hr);
        const int offy = pm / wr;
        prm[p].size = size;
        prm[p].offy = offy;
        prm[p].offx = pm - offy * wr;
        prm[p].pad  = 0;
    }
}

// One wave (64 lanes) per output row (p,s,c,o). 4 waves per block.
// Phase 1: coalesced vertical sum of the bin's <=5 rows into 128 column sums
//          (lane l owns columns l and l+64), staged in a per-wave LDS slice.
// Phase 2: lanes 0..31 compute the <=5-wide horizontal bin sums, one 128B
//          contiguous store per wave.
__global__ __launch_bounds__(256) void patch_pool_kernel(
    const float*  __restrict__ input,     // [P,S,C,H,W]
    const int*    __restrict__ channels,  // [P,NC]
    const Params* __restrict__ prm,       // [P]
    float*        __restrict__ out)       // [P,S,NC,O,O]
{
    __shared__ float cols[4][128];

    const int w    = threadIdx.x >> 6;    // wave id within block
    const int lane = threadIdx.x & 63;
    const int R    = blockIdx.x * 4 + w;  // global output-row id
    const int o = R & (OO - 1);
    const int c = (R >> 5) & (NC - 1);
    const int s = (R >> 10) & (SS - 1);
    const int p = R >> 12;

    const Params pr = prm[p];
    const int size = pr.size;
    const int ch = channels[p * NC + c];

    const int sy = (o * size) >> 5;
    const int ey = ((o + 1) * size + 31) >> 5;
    const int rows = ey - sy;             // 1..5

    const float* base = input
        + ((size_t)((p * SS + s) * CC + ch)) * (HH * WW)
        + (pr.offy + sy) * WW + pr.offx;

    float cs0 = 0.0f, cs1 = 0.0f;
    for (int r = 0; r < rows; ++r) {
        const float* row = base + r * WW;
        if (lane < size)      cs0 += row[lane];
        if (lane + 64 < size) cs1 += row[lane + 64];
    }
    cols[w][lane]      = cs0;
    cols[w][lane + 64] = cs1;
    __syncthreads();

    if (lane < OO) {
        const int q  = lane;
        const int sx = (q * size) >> 5;
        const int ex = ((q + 1) * size + 31) >> 5;
        float a = 0.0f;
        for (int x = sx; x < ex; ++x) a += cols[w][x];
        out[(size_t)R * OO + q] = a / (float)(rows * (ex - sx));
    }
}

extern "C" void kernel_launch(void* const* d_in, const int* in_sizes, int n_in,
                              void* d_out, int out_size, void* d_ws, size_t ws_size,
                              hipStream_t stream) {
    const float* input    = (const float*)d_in[0];
    const int*   size_raw = (const int*)d_in[1];
    const int*   pix      = (const int*)d_in[2];
    const int*   channels = (const int*)d_in[3];
    float*       out      = (float*)d_out;
    Params*      prm      = (Params*)d_ws;   // 512 bytes used

    setup_params_kernel<<<1, 64, 0, stream>>>(size_raw, pix, prm);

    const int total_rows = PP * SS * NC * OO;   // 131072
    const int grid = total_rows / 4;            // 32768 blocks of 4 waves
    patch_pool_kernel<<<grid, 256, 0, stream>>>(input, channels, prm, out);
}

// Round 4
// 58.083 us; speedup vs baseline: 1.1064x; 1.1064x over previous
//
#include <hip/hip_runtime.h>

// Problem constants (match reference)
#define PP 32   // patches
#define SS 4
#define CC 64
#define HH 128
#define WW 128
#define NC 32   // channels kept per patch
#define OO 32   // adaptive pool output size (MIN_SIZE)

// ws layout: int cbase[PP*NC]; int psize[PP];
// cbase[p*NC+c] = element offset of (p, s=0, channels[p][c]) plane + crop origin.
__global__ __launch_bounds__(256) void setup_kernel(
    const int* __restrict__ size_raw,
    const int* __restrict__ pix,
    const int* __restrict__ channels,
    int*       __restrict__ cbase,     // [PP*NC]
    int*       __restrict__ psize)     // [PP]
{
    const int i = blockIdx.x * 256 + threadIdx.x;   // 0..1023
    const int p = i >> 5;
    const int c = i & 31;
    const int size = size_raw[p] + OO;              // [32,128]
    const int wr = WW - size + 1;
    const int hr = HH - size + 1;
    const int pm = pix[p] % (wr * hr);
    const int offy = pm / wr;
    const int offx = pm - offy * wr;
    if (c == 0) psize[p] = size;
    const int ch = channels[p * NC + c];
    cbase[i] = (p * SS * CC + ch) * (HH * WW) + offy * WW + offx;
}

// Sum an up-to-MxM bin with all loads independent (clamped into the bin,
// masked accumulate). All M*M loads issue before any dependent add -> deep
// memory-level parallelism per wave.
template <int M>
__device__ __forceinline__ float binsum(const float* __restrict__ ptr,
                                        int rows, int cols)
{
    float acc = 0.0f;
    #pragma unroll
    for (int dy = 0; dy < M; ++dy) {
        const int iy = (dy < rows) ? dy : (rows - 1);
        #pragma unroll
        for (int dx = 0; dx < M; ++dx) {
            const int ix = (dx < cols) ? dx : (cols - 1);
            const float v = ptr[iy * WW + ix];
            acc += ((dy < rows) && (dx < cols)) ? v : 0.0f;
        }
    }
    return acc;
}

// One thread per output element. idx = ((((p*S+s)*NC+c)*O)+o)*O + q
__global__ __launch_bounds__(256) void pool_kernel(
    const float* __restrict__ input,   // [P,S,C,H,W]
    const int*   __restrict__ cbase,   // [PP*NC]
    const int*   __restrict__ psize,   // [PP]
    float*       __restrict__ out)     // [P,S,NC,O,O]
{
    const int idx = blockIdx.x * 256 + threadIdx.x;
    const int q = idx & (OO - 1);
    const int o = (idx >> 5) & (OO - 1);
    const int c = (idx >> 10) & (NC - 1);
    const int s = (idx >> 15) & (SS - 1);
    const int p = idx >> 17;

    const int size = psize[p];                       // wave-uniform
    const int sy = (o * size) >> 5;
    const int ey = ((o + 1) * size + 31) >> 5;
    const int sx = (q * size) >> 5;
    const int ex = ((q + 1) * size + 31) >> 5;
    const int rows = ey - sy;                        // 1..5
    const int cols = ex - sx;                        // 1..5

    const float* ptr = input + cbase[(p << 5) | c] + s * (CC * HH * WW)
                     + sy * WW + sx;

    // Max bin extent for this size (wave-uniform): exact if 32|size, else +2.
    const int Mreq = (size & 31) ? ((size >> 5) + 2) : (size >> 5);

    float acc;
    if (Mreq <= 3)      acc = binsum<3>(ptr, rows, cols);
    else if (Mreq == 4) acc = binsum<4>(ptr, rows, cols);
    else                acc = binsum<5>(ptr, rows, cols);

    out[idx] = acc * __builtin_amdgcn_rcpf((float)(rows * cols));
}

extern "C" void kernel_launch(void* const* d_in, const int* in_sizes, int n_in,
                              void* d_out, int out_size, void* d_ws, size_t ws_size,
                              hipStream_t stream) {
    const float* input    = (const float*)d_in[0];
    const int*   size_raw = (const int*)d_in[1];
    const int*   pix      = (const int*)d_in[2];
    const int*   channels = (const int*)d_in[3];
    float*       out      = (float*)d_out;

    int* cbase = (int*)d_ws;            // 1024 ints
    int* psize = cbase + PP * NC;       // 32 ints

    setup_kernel<<<4, 256, 0, stream>>>(size_raw, pix, channels, cbase, psize);

    const int total = PP * SS * NC * OO * OO;   // 4,194,304
    pool_kernel<<<total / 256, 256, 0, stream>>>(input, cbase, psize, out);
}

// Round 5
// 55.063 us; speedup vs baseline: 1.1670x; 1.0548x over previous
//
#include <hip/hip_runtime.h>

// Problem constants (match reference)
#define PP 32   // patches
#define SS 4
#define CC 64
#define HH 128
#define WW 128
#define NC 32   // channels kept per patch
#define OO 32   // adaptive pool output size (MIN_SIZE)
#define PLANE (HH * WW)                 // 16384
#define NTOT (PP * SS * CC * PLANE)     // total input elements

// ws: int cbase[PP*NC]; int psize[PP]; int poffx[PP]
__global__ __launch_bounds__(256) void setup_kernel(
    const int* __restrict__ size_raw,
    const int* __restrict__ pix,
    const int* __restrict__ channels,
    int* __restrict__ cbase,   // [PP*NC] plane offset + offy rows (no offx)
    int* __restrict__ psize,   // [PP]
    int* __restrict__ poffx)   // [PP]
{
    const int i = blockIdx.x * 256 + threadIdx.x;   // 0..1023
    const int p = i >> 5;
    const int c = i & 31;
    const int size = size_raw[p] + OO;              // [32,128]
    const int wr = WW - size + 1;
    const int hr = HH - size + 1;
    const int pm = pix[p] % (wr * hr);
    const int offy = pm / wr;
    const int offx = pm - offy * wr;
    if (c == 0) { psize[p] = size; poffx[p] = offx; }
    const int ch = channels[p * NC + c];
    cbase[i] = (p * SS * CC + ch) * PLANE + offy * WW;
}

// Component select for the 20-float register window (u compile-time).
#define RV(u) (((u) & 3) == 0 ? rs[(u) >> 2].x : ((u) & 3) == 1 ? rs[(u) >> 2].y \
             : ((u) & 3) == 2 ? rs[(u) >> 2].z : rs[(u) >> 2].w)

// One thread per 4 consecutive q outputs. t -> (p,s,c,o,qg), q = 4*qg..4*qg+3.
// Loads: <=5 rows x <=5 aligned float4 covering the 4 bins' column span,
// fully unrolled + predicated -> deep MLP, 16B/lane, minimal vmem instrs.
__global__ __launch_bounds__(256) void pool_kernel(
    const float* __restrict__ input,
    const int*   __restrict__ cbase,
    const int*   __restrict__ psize,
    const int*   __restrict__ poffx,
    float*       __restrict__ out)
{
    const int t = blockIdx.x * 256 + threadIdx.x;   // 0..2^20-1
    const int qg = t & 7;
    const int o  = (t >> 3) & 31;
    const int c  = (t >> 8) & 31;
    const int s  = (t >> 13) & 3;
    const int p  = t >> 15;

    const int size = psize[p];      // wave-uniform
    const int offx = poffx[p];
    const int q0 = qg << 2;

    const int sy   = (o * size) >> 5;
    const int rows = (((o + 1) * size + 31) >> 5) - sy;        // 1..5

    const int sx0 = (q0 * size) >> 5;
    const int ax  = offx + sx0;
    const int A   = ax & ~3;         // 16B-aligned start col
    const int sh  = ax & 3;          // shift into the register window

    // bin windows in window-local coords u (b0 = sh)
    const int b1 = sh + ((((q0 + 1) * size) >> 5) - sx0);
    const int b2 = sh + ((((q0 + 2) * size) >> 5) - sx0);
    const int b3 = sh + ((((q0 + 3) * size) >> 5) - sx0);
    const int e0 = sh + ((((q0 + 1) * size + 31) >> 5) - sx0);
    const int e1 = sh + ((((q0 + 2) * size + 31) >> 5) - sx0);
    const int e2 = sh + ((((q0 + 3) * size + 31) >> 5) - sx0);
    const int e3 = sh + ((((q0 + 4) * size + 31) >> 5) - sx0); // = U <= 20
    const int U  = e3;

    const float* base = input + cbase[(p << 5) | c] + s * (CC * PLANE)
                      + sy * WW + A;
    const float* lim = input + (NTOT - 4);

    float4 rs[5];
    #pragma unroll
    for (int k = 0; k < 5; ++k) rs[k] = make_float4(0.f, 0.f, 0.f, 0.f);

    #pragma unroll
    for (int dy = 0; dy < 5; ++dy) {
        if (dy < rows) {
            #pragma unroll
            for (int k = 0; k < 5; ++k) {
                if ((k << 2) < U) {
                    const float* pk = base + dy * WW + (k << 2);
                    const float* pc = (pk > lim) ? lim : pk;   // end-of-array guard
                    float4 v = *(const float4*)pc;
                    const int d = (int)(pk - pc);              // 0 except last 16B of input
                    if (d) {                                   // rare: realign components
                        const float a1 = v.y, a2 = v.z, a3 = v.w;
                        v.x = (d == 1) ? a1 : (d == 2) ? a2 : a3;
                        v.y = (d == 1) ? a2 : (d == 2) ? a3 : 0.f;
                        v.z = (d == 1) ? a3 : 0.f;
                        v.w = 0.f;
                    }
                    rs[k].x += v.x; rs[k].y += v.y; rs[k].z += v.z; rs[k].w += v.w;
                }
            }
        }
    }

    float acc0 = 0.f, acc1 = 0.f, acc2 = 0.f, acc3 = 0.f;
    #pragma unroll
    for (int u = 0; u < 20; ++u) {
        const float v = RV(u);
        acc0 += (u >= sh && u < e0) ? v : 0.f;
        acc1 += (u >= b1 && u < e1) ? v : 0.f;
        acc2 += (u >= b2 && u < e2) ? v : 0.f;
        acc3 += (u >= b3 && u < e3) ? v : 0.f;
    }

    const float fr = (float)rows;
    float4 res;
    res.x = acc0 * __builtin_amdgcn_rcpf(fr * (float)(e0 - sh));
    res.y = acc1 * __builtin_amdgcn_rcpf(fr * (float)(e1 - b1));
    res.z = acc2 * __builtin_amdgcn_rcpf(fr * (float)(e2 - b2));
    res.w = acc3 * __builtin_amdgcn_rcpf(fr * (float)(e3 - b3));
    *(float4*)(out + ((size_t)t << 2)) = res;
}

extern "C" void kernel_launch(void* const* d_in, const int* in_sizes, int n_in,
                              void* d_out, int out_size, void* d_ws, size_t ws_size,
                              hipStream_t stream) {
    const float* input    = (const float*)d_in[0];
    const int*   size_raw = (const int*)d_in[1];
    const int*   pix      = (const int*)d_in[2];
    const int*   channels = (const int*)d_in[3];
    float*       out      = (float*)d_out;

    int* cbase = (int*)d_ws;             // 1024 ints
    int* psize = cbase + PP * NC;        // 32 ints
    int* poffx = psize + PP;             // 32 ints

    setup_kernel<<<4, 256, 0, stream>>>(size_raw, pix, channels, cbase, psize, poffx);

    const int total_threads = (PP * SS * NC * OO * OO) / 4;   // 1,048,576
    pool_kernel<<<total_threads / 256, 256, 0, stream>>>(input, cbase, psize, poffx, out);
}